// Round 3
// baseline (7404.560 us; speedup 1.0000x reference)
//
#include <hip/hip_runtime.h>

typedef short short8 __attribute__((ext_vector_type(8)));
typedef short short4v __attribute__((ext_vector_type(4)));
typedef float float4v __attribute__((ext_vector_type(4)));
typedef __bf16 bf16x8 __attribute__((ext_vector_type(8)));

#define NA_ 100000
#define NS_ 50000
#define DD_ 256
#define HH_ 128
#define EAA_ 800000
#define ESS_ 400000
#define ESA_ 800000

static __device__ __forceinline__ float b2f(short s) {
  unsigned int u = ((unsigned int)(unsigned short)s) << 16;
  return __builtin_bit_cast(float, u);
}
static __device__ __forceinline__ short f2b(float f) {
  unsigned int u = __builtin_bit_cast(unsigned int, f);
  u = u + 0x7FFFu + ((u >> 16) & 1u);
  return (short)(u >> 16);
}

// ---------------- init ----------------
__global__ void init_degs_k(int* deg_aa, int* deg_ss, int* cnt_sa) {
  int i = blockIdx.x * 256 + threadIdx.x;
  if (i < NA_) { deg_aa[i] = 1; cnt_sa[i] = 0; }
  if (i < NS_) { deg_ss[i] = 1; }
}

// ---------------- W transpose+convert: W fp32 [256][128] -> Wt bf16 [128][256] ----------------
__global__ void transpose_w_k(const float* __restrict__ W, short* __restrict__ Wt) {
  int tid = blockIdx.x * 256 + threadIdx.x;  // 32768 total
  int k = tid >> 7, n = tid & 127;
  Wt[n * 256 + k] = f2b(W[k * 128 + n]);
}

// ---------------- GEMM: C[M,128] = A[M,256] @ Wt^T (A fp32, Wt bf16 [128][256]) ----------------
// F32OUT=true stores fp32; else bf16.
#define LDN 136  // LDS row stride: 128 + 8 pad -> 2-way bank alias (free)
template <bool F32OUT>
__global__ __launch_bounds__(256) void gemm_t(const float* __restrict__ A,
                                              const short* __restrict__ Wt,
                                              void* __restrict__ Cv, int M) {
  __shared__ short lds[128 * LDN];
  int tid = threadIdx.x;
  int wave = tid >> 6, lane = tid & 63;
  int l16 = lane & 15, lq = lane >> 4;
  int rowBase = blockIdx.x * 256 + wave * 64;

  float4v acc[4][8];
#pragma unroll
  for (int rt = 0; rt < 4; ++rt)
#pragma unroll
    for (int ct = 0; ct < 8; ++ct) acc[rt][ct] = (float4v){0.f, 0.f, 0.f, 0.f};

  for (int phase = 0; phase < 2; ++phase) {
    int kg = phase * 128;
    __syncthreads();
    for (int idx = tid; idx < 128 * 16; idx += 256) {
      int n = idx >> 4, c = idx & 15;
      *(short8*)&lds[n * LDN + c * 8] = *(const short8*)&Wt[n * 256 + kg + c * 8];
    }
    __syncthreads();
#pragma unroll
    for (int ks = 0; ks < 4; ++ks) {
      int k0 = kg + ks * 32;
      short8 af[4];
#pragma unroll
      for (int rt = 0; rt < 4; ++rt) {
        int row = rowBase + rt * 16 + l16;
        if (row >= M) row = M - 1;
        const float* ap = &A[(long)row * 256 + k0 + lq * 8];
        float4v a0 = *(const float4v*)ap;
        float4v a1 = *(const float4v*)(ap + 4);
#pragma unroll
        for (int j = 0; j < 4; ++j) {
          af[rt][j] = f2b(a0[j]);
          af[rt][4 + j] = f2b(a1[j]);
        }
      }
#pragma unroll
      for (int ct = 0; ct < 8; ++ct) {
        short8 bfg = *(const short8*)&lds[(ct * 16 + l16) * LDN + ks * 32 + lq * 8];
#pragma unroll
        for (int rt = 0; rt < 4; ++rt) {
          acc[rt][ct] = __builtin_amdgcn_mfma_f32_16x16x32_bf16(
              __builtin_bit_cast(bf16x8, af[rt]), __builtin_bit_cast(bf16x8, bfg),
              acc[rt][ct], 0, 0, 0);
        }
      }
    }
  }
#pragma unroll
  for (int rt = 0; rt < 4; ++rt) {
    int r0 = rowBase + rt * 16 + lq * 4;
#pragma unroll
    for (int ct = 0; ct < 8; ++ct) {
      int col = ct * 16 + l16;
#pragma unroll
      for (int r = 0; r < 4; ++r) {
        int row = r0 + r;
        if (row < M) {
          if (F32OUT)
            ((float*)Cv)[(long)row * 128 + col] = acc[rt][ct][r];
          else
            ((short*)Cv)[(long)row * 128 + col] = f2b(acc[rt][ct][r]);
        }
      }
    }
  }
}

// ---------------- degree / weights ----------------
__global__ void count_edges_k(const int* __restrict__ dst, int* __restrict__ deg, int E) {
  int i = blockIdx.x * 256 + threadIdx.x;
  if (i < E) atomicAdd(&deg[dst[i]], 1);
}
__global__ void dinv_k(const int* __restrict__ deg, float* __restrict__ dinv, int n) {
  int i = blockIdx.x * 256 + threadIdx.x;
  if (i < n) dinv[i] = rsqrtf((float)deg[i]);
}
__global__ void invc_k(const int* __restrict__ cnt, float* __restrict__ invc, int n) {
  int i = blockIdx.x * 256 + threadIdx.x;
  if (i < n) invc[i] = 1.0f / fmaxf((float)cnt[i], 1.0f);
}

// ---------------- edge scatters (atomic fp32), 16 threads/edge ----------------
__global__ void gcn_scatter_k(const short* __restrict__ h, const int* __restrict__ src,
                              const int* __restrict__ dst, const float* __restrict__ dinv,
                              float* __restrict__ acc, int E) {
  int tid = blockIdx.x * 256 + threadIdx.x;
  int e = tid >> 4, part = tid & 15;
  if (e >= E) return;
  int s = src[e], d = dst[e];
  float w = dinv[s] * dinv[d];
  short8 hv = *(const short8*)&h[(long)s * 128 + part * 8];
  float* ap = acc + (long)d * 128 + part * 8;
#pragma unroll
  for (int i = 0; i < 8; ++i) atomicAdd(ap + i, b2f(hv[i]) * w);
}
__global__ void sage_scatter_k(const short* __restrict__ y, const int* __restrict__ src,
                               const int* __restrict__ dst, const float* __restrict__ invc,
                               float* __restrict__ acc, int E) {
  int tid = blockIdx.x * 256 + threadIdx.x;
  int e = tid >> 4, part = tid & 15;
  if (e >= E) return;
  int s = src[e], d = dst[e];
  float w = invc[d];
  short8 yv = *(const short8*)&y[(long)s * 128 + part * 8];
  float* ap = acc + (long)d * 128 + part * 8;
#pragma unroll
  for (int i = 0; i < 8; ++i) atomicAdd(ap + i, b2f(yv[i]) * w);
}

// ---------------- finalize (fp32 out) ----------------
__global__ void finalize_art_k(const float* __restrict__ acc, const short* __restrict__ h,
                               const float* __restrict__ dinv, const float* __restrict__ b_aa,
                               const float* __restrict__ b_sal, float* __restrict__ out) {
  int tid = blockIdx.x * 256 + threadIdx.x;
  int i = tid >> 5, q = tid & 31;
  if (i >= NA_) return;
  long base = (long)i * 128 + q * 4;
  float di = dinv[i];
  float d2 = di * di;
  float4v av = *(const float4v*)(acc + base);
  short4v hv = *(const short4v*)(h + base);
  float4v ba = *(const float4v*)(b_aa + q * 4);
  float4v bl = *(const float4v*)(b_sal + q * 4);
  float4v res;
#pragma unroll
  for (int x = 0; x < 4; ++x) {
    float o = 0.5f * (av[x] + b2f(hv[x]) * d2 + ba[x] + bl[x]);
    res[x] = fmaxf(o, 0.0f);
  }
  *(float4v*)(out + base) = res;
}
__global__ void finalize_soft_k(const float* __restrict__ acc, const short* __restrict__ h,
                                const float* __restrict__ dinv, const float* __restrict__ b_ss,
                                float* __restrict__ out) {
  int tid = blockIdx.x * 256 + threadIdx.x;
  int i = tid >> 5, q = tid & 31;
  if (i >= NS_) return;
  long base = (long)i * 128 + q * 4;
  float di = dinv[i];
  float d2 = di * di;
  float4v av = *(const float4v*)(acc + base);
  short4v hv = *(const short4v*)(h + base);
  float4v bs = *(const float4v*)(b_ss + q * 4);
  float4v res;
#pragma unroll
  for (int x = 0; x < 4; ++x) {
    float o = av[x] + b2f(hv[x]) * d2 + bs[x];
    res[x] = fmaxf(o, 0.0f);
  }
  *(float4v*)(out + base) = res;
}

extern "C" void kernel_launch(void* const* d_in, const int* in_sizes, int n_in,
                              void* d_out, int out_size, void* d_ws, size_t ws_size,
                              hipStream_t stream) {
  const float* x_a = (const float*)d_in[0];
  const float* x_s = (const float*)d_in[1];
  const int* ei_aa = (const int*)d_in[2];
  const int* ei_ss = (const int*)d_in[3];
  const int* sa_src = (const int*)d_in[4];
  const int* sa_dst = (const int*)d_in[5];
  const float* W_aa = (const float*)d_in[6];
  const float* b_aa = (const float*)d_in[7];
  const float* W_ss = (const float*)d_in[8];
  const float* b_ss = (const float*)d_in[9];
  const float* W_sal = (const float*)d_in[10];
  const float* b_sal = (const float*)d_in[11];
  const float* W_sar = (const float*)d_in[12];

  const int* src_aa = ei_aa;
  const int* dst_aa = ei_aa + EAA_;
  const int* src_ss = ei_ss;
  const int* dst_ss = ei_ss + ESS_;

  // ---- workspace layout (aliased across phases); peak ~92 MB ----
  char* base = (char*)d_ws;
  size_t off = 0;
  auto alloc = [&](size_t bytes) {
    void* p = base + off;
    off += (bytes + 511) & ~(size_t)511;
    return p;
  };
  float* accR = (float*)alloc((size_t)NA_ * 128 * 4);  // 51.2 MB
  short* hR = (short*)alloc((size_t)NA_ * 128 * 2);    // 25.6 MB
  short* y_sl = (short*)alloc((size_t)NS_ * 128 * 2);  // 12.8 MB
  int* deg_aa = (int*)alloc((size_t)NA_ * 4);
  int* deg_ss = (int*)alloc((size_t)NS_ * 4);
  int* cnt_sa = (int*)alloc((size_t)NA_ * 4);
  float* dinv_aa = (float*)alloc((size_t)NA_ * 4);
  float* dinv_ss = (float*)alloc((size_t)NS_ * 4);
  float* invc_sa = (float*)alloc((size_t)NA_ * 4);
  short* Wt_aa = (short*)alloc(128 * 256 * 2);
  short* Wt_ss = (short*)alloc(128 * 256 * 2);
  short* Wt_sal = (short*)alloc(128 * 256 * 2);
  short* Wt_sar = (short*)alloc(128 * 256 * 2);

  float* acc_ss = accR;
  float* acc_art = accR;
  short* h_ss = hR;
  short* h_aa = hR;

  float* out_art = (float*)d_out;
  float* out_soft = (float*)d_out + (size_t)NA_ * 128;

  int gA = (NA_ + 255) / 256, gS = (NS_ + 255) / 256;

  // ---- prep: degrees, weights, transposes ----
  hipMemsetAsync(acc_ss, 0, (size_t)NS_ * 128 * 4, stream);  // zero soft accumulator
  init_degs_k<<<(NA_ + 255) / 256, 256, 0, stream>>>(deg_aa, deg_ss, cnt_sa);
  transpose_w_k<<<128, 256, 0, stream>>>(W_aa, Wt_aa);
  transpose_w_k<<<128, 256, 0, stream>>>(W_ss, Wt_ss);
  transpose_w_k<<<128, 256, 0, stream>>>(W_sal, Wt_sal);
  transpose_w_k<<<128, 256, 0, stream>>>(W_sar, Wt_sar);
  count_edges_k<<<(EAA_ + 255) / 256, 256, 0, stream>>>(dst_aa, deg_aa, EAA_);
  count_edges_k<<<(ESS_ + 255) / 256, 256, 0, stream>>>(dst_ss, deg_ss, ESS_);
  count_edges_k<<<(ESA_ + 255) / 256, 256, 0, stream>>>(sa_dst, cnt_sa, ESA_);
  dinv_k<<<(NA_ + 255) / 256, 256, 0, stream>>>(deg_aa, dinv_aa, NA_);
  dinv_k<<<(NS_ + 255) / 256, 256, 0, stream>>>(deg_ss, dinv_ss, NS_);
  invc_k<<<(NA_ + 255) / 256, 256, 0, stream>>>(cnt_sa, invc_sa, NA_);

  // ---- phase S: software output ----
  gemm_t<false><<<gS, 256, 0, stream>>>(x_s, Wt_ss, h_ss, NS_);
  gcn_scatter_k<<<ESS_ / 16, 256, 0, stream>>>(h_ss, src_ss, dst_ss, dinv_ss, acc_ss, ESS_);
  finalize_soft_k<<<(NS_ * 32) / 256, 256, 0, stream>>>(acc_ss, h_ss, dinv_ss, b_ss, out_soft);

  // ---- phase A: article output (reuses accR / hR after phase S) ----
  gemm_t<true><<<gA, 256, 0, stream>>>(x_a, Wt_sar, acc_art, NA_);   // fp32 init of acc
  gemm_t<false><<<gA, 256, 0, stream>>>(x_a, Wt_aa, h_aa, NA_);
  gemm_t<false><<<gS, 256, 0, stream>>>(x_s, Wt_sal, y_sl, NS_);
  gcn_scatter_k<<<EAA_ / 16, 256, 0, stream>>>(h_aa, src_aa, dst_aa, dinv_aa, acc_art, EAA_);
  sage_scatter_k<<<ESA_ / 16, 256, 0, stream>>>(y_sl, sa_src, sa_dst, invc_sa, acc_art, ESA_);
  finalize_art_k<<<(NA_ * 32) / 256, 256, 0, stream>>>(acc_art, h_aa, dinv_aa, b_aa, b_sal,
                                                       out_art);
}

// Round 4
// 749.288 us; speedup vs baseline: 9.8821x; 9.8821x over previous
//
#include <hip/hip_runtime.h>

typedef short short8 __attribute__((ext_vector_type(8)));
typedef float float4v __attribute__((ext_vector_type(4)));
typedef __bf16 bf16x8 __attribute__((ext_vector_type(8)));

#define NA_ 100000
#define NS_ 50000
#define DD_ 256
#define HH_ 128
#define EAA_ 800000
#define ESS_ 400000
#define ESA_ 800000
// concatenated node index space for CSR: [aa: 0..NA_), [sa: NA_..2*NA_), [ss: 2*NA_..2*NA_+NS_)
#define NNODES_ (NA_ + NA_ + NS_)   // 250000
#define SCAN_BLOCKS_ 62             // 62*4096 = 253952 >= NNODES_
#define NPAD_ (SCAN_BLOCKS_ * 4096)

static __device__ __forceinline__ float b2f(short s) {
  unsigned int u = ((unsigned int)(unsigned short)s) << 16;
  return __builtin_bit_cast(float, u);
}
static __device__ __forceinline__ short f2b(float f) {
  unsigned int u = __builtin_bit_cast(unsigned int, f);
  u = u + 0x7FFFu + ((u >> 16) & 1u);
  return (short)(u >> 16);
}

// ---------------- W transpose+convert: W fp32 [256][128] -> Wt bf16 [128][256] ----------------
__global__ void transpose_w_k(const float* __restrict__ W, short* __restrict__ Wt) {
  int tid = blockIdx.x * 256 + threadIdx.x;  // 32768 total
  int k = tid >> 7, n = tid & 127;
  Wt[n * 256 + k] = f2b(W[k * 128 + n]);
}

// ---------------- GEMM: C[M,128] = A[M,256] @ Wt^T (A fp32, Wt bf16 [128][256]), bf16 out ----
#define LDN 136
__global__ __launch_bounds__(256) void gemm_k(const float* __restrict__ A,
                                              const short* __restrict__ Wt,
                                              short* __restrict__ C, int M) {
  __shared__ short lds[128 * LDN];
  int tid = threadIdx.x;
  int wave = tid >> 6, lane = tid & 63;
  int l16 = lane & 15, lq = lane >> 4;
  int rowBase = blockIdx.x * 256 + wave * 64;

  float4v acc[4][8];
#pragma unroll
  for (int rt = 0; rt < 4; ++rt)
#pragma unroll
    for (int ct = 0; ct < 8; ++ct) acc[rt][ct] = (float4v){0.f, 0.f, 0.f, 0.f};

  for (int phase = 0; phase < 2; ++phase) {
    int kg = phase * 128;
    __syncthreads();
    for (int idx = tid; idx < 128 * 16; idx += 256) {
      int n = idx >> 4, c = idx & 15;
      *(short8*)&lds[n * LDN + c * 8] = *(const short8*)&Wt[n * 256 + kg + c * 8];
    }
    __syncthreads();
#pragma unroll
    for (int ks = 0; ks < 4; ++ks) {
      int k0 = kg + ks * 32;
      short8 af[4];
#pragma unroll
      for (int rt = 0; rt < 4; ++rt) {
        int row = rowBase + rt * 16 + l16;
        if (row >= M) row = M - 1;
        const float* ap = &A[(long)row * 256 + k0 + lq * 8];
        float4v a0 = *(const float4v*)ap;
        float4v a1 = *(const float4v*)(ap + 4);
#pragma unroll
        for (int j = 0; j < 4; ++j) {
          af[rt][j] = f2b(a0[j]);
          af[rt][4 + j] = f2b(a1[j]);
        }
      }
#pragma unroll
      for (int ct = 0; ct < 8; ++ct) {
        short8 bfg = *(const short8*)&lds[(ct * 16 + l16) * LDN + ks * 32 + lq * 8];
#pragma unroll
        for (int rt = 0; rt < 4; ++rt) {
          acc[rt][ct] = __builtin_amdgcn_mfma_f32_16x16x32_bf16(
              __builtin_bit_cast(bf16x8, af[rt]), __builtin_bit_cast(bf16x8, bfg),
              acc[rt][ct], 0, 0, 0);
        }
      }
    }
  }
#pragma unroll
  for (int rt = 0; rt < 4; ++rt) {
    int r0 = rowBase + rt * 16 + lq * 4;
#pragma unroll
    for (int ct = 0; ct < 8; ++ct) {
      int col = ct * 16 + l16;
#pragma unroll
      for (int r = 0; r < 4; ++r) {
        int row = r0 + r;
        if (row < M) C[(long)row * 128 + col] = f2b(acc[rt][ct][r]);
      }
    }
  }
}

// ---------------- CSR build ----------------
__global__ void count_k(const int* __restrict__ dst, int* __restrict__ cnt, int E) {
  int i = blockIdx.x * 256 + threadIdx.x;
  if (i < E) atomicAdd(&cnt[dst[i]], 1);
}

// scanA: per-block (4096 elems) exclusive scan -> part[], block sums -> bsums[]
__global__ void scanA_k(const int* __restrict__ in, int* __restrict__ part,
                        int* __restrict__ bsums) {
  __shared__ int lds[256];
  int t = threadIdx.x, b = blockIdx.x;
  int base = b * 4096 + t * 16;
  int v[16];
  int run = 0;
#pragma unroll
  for (int j = 0; j < 16; ++j) {
    int x = (base + j < NNODES_) ? in[base + j] : 0;
    v[j] = run;
    run += x;
  }
  lds[t] = run;
  __syncthreads();
  int incl = run;
  for (int off = 1; off < 256; off <<= 1) {
    int add = (t >= off) ? lds[t - off] : 0;
    __syncthreads();
    lds[t] += add;
    incl = lds[t];
    __syncthreads();
  }
  int excl = incl - run;
#pragma unroll
  for (int j = 0; j < 16; ++j) part[base + j] = v[j] + excl;
  if (t == 255) bsums[b] = incl;
}
// scanB: exclusive scan of SCAN_BLOCKS_ block sums (single block)
__global__ void scanB_k(int* __restrict__ bsums) {
  __shared__ int lds[256];
  int t = threadIdx.x;
  int v = (t < SCAN_BLOCKS_) ? bsums[t] : 0;
  lds[t] = v;
  __syncthreads();
  int incl = v;
  for (int off = 1; off < 256; off <<= 1) {
    int add = (t >= off) ? lds[t - off] : 0;
    __syncthreads();
    lds[t] += add;
    incl = lds[t];
    __syncthreads();
  }
  if (t < SCAN_BLOCKS_) bsums[t] = incl - v;
}
// scanC: add block offsets, write row_ptr + cursor
__global__ void scanC_k(const int* __restrict__ part, const int* __restrict__ bsums,
                        int* __restrict__ row_ptr, int* __restrict__ cursor) {
  int t = threadIdx.x, b = blockIdx.x;
  int base = b * 4096 + t * 16;
  int sb = bsums[b];
#pragma unroll
  for (int j = 0; j < 16; ++j) {
    int val = part[base + j] + sb;
    row_ptr[base + j] = val;
    cursor[base + j] = val;
  }
}
// fill: scatter edge src ids into CSR pool
__global__ void fill_k(const int* __restrict__ src, const int* __restrict__ dst,
                       int* __restrict__ cursor, int nodeBase, int* __restrict__ pool, int E) {
  int i = blockIdx.x * 256 + threadIdx.x;
  if (i >= E) return;
  int pos = atomicAdd(&cursor[nodeBase + dst[i]], 1);
  pool[pos] = src[i];
}

// ---------------- norms ----------------
__global__ void norms_k(const int* __restrict__ cnt, float* __restrict__ dinv_aa,
                        float* __restrict__ dinv_ss, float* __restrict__ invc_sa) {
  int i = blockIdx.x * 256 + threadIdx.x;
  if (i < NA_) {
    dinv_aa[i] = rsqrtf((float)(cnt[i] + 1));
    invc_sa[i] = 1.0f / fmaxf((float)cnt[NA_ + i], 1.0f);
  }
  if (i < NS_) dinv_ss[i] = rsqrtf((float)(cnt[2 * NA_ + i] + 1));
}

// ---------------- fused gathers (one wave per dst node, 2 cols/lane) ----------------
__global__ __launch_bounds__(256) void gather_art_k(
    const short* __restrict__ h_aa, const short* __restrict__ y_sl,
    const short* __restrict__ r_a, const int* __restrict__ pool,
    const int* __restrict__ row_ptr, const float* __restrict__ dinv_aa,
    const float* __restrict__ invc_sa, const float* __restrict__ b_aa,
    const float* __restrict__ b_sal, float* __restrict__ out) {
  int wave = threadIdx.x >> 6, lane = threadIdx.x & 63;
  int d = blockIdx.x * 4 + wave;
  if (d >= NA_) return;
  int c = lane * 2;
  float dd = dinv_aa[d];
  // GCN aa neighbors
  float a0 = 0.f, a1 = 0.f;
  int r0 = row_ptr[d], r1 = row_ptr[d + 1];
  for (int j = r0; j < r1; ++j) {
    int s = pool[j];
    float w = dinv_aa[s] * dd;
    short2 hv = *(const short2*)&h_aa[(long)s * 128 + c];
    a0 += b2f(hv.x) * w;
    a1 += b2f(hv.y) * w;
  }
  // SAGE sa neighbors
  float s0 = 0.f, s1 = 0.f;
  r0 = row_ptr[NA_ + d];
  r1 = row_ptr[NA_ + d + 1];
  for (int j = r0; j < r1; ++j) {
    int s = pool[j];
    short2 yv = *(const short2*)&y_sl[(long)s * 128 + c];
    s0 += b2f(yv.x);
    s1 += b2f(yv.y);
  }
  float ic = invc_sa[d];
  float d2 = dd * dd;
  short2 hv = *(const short2*)&h_aa[(long)d * 128 + c];
  short2 rv = *(const short2*)&r_a[(long)d * 128 + c];
  float2 ba = *(const float2*)&b_aa[c];
  float2 bl = *(const float2*)&b_sal[c];
  float o0 = 0.5f * ((a0 + b2f(hv.x) * d2 + ba.x) + (s0 * ic + bl.x + b2f(rv.x)));
  float o1 = 0.5f * ((a1 + b2f(hv.y) * d2 + ba.y) + (s1 * ic + bl.y + b2f(rv.y)));
  float2 res = make_float2(fmaxf(o0, 0.f), fmaxf(o1, 0.f));
  *(float2*)&out[(long)d * 128 + c] = res;
}

__global__ __launch_bounds__(256) void gather_soft_k(
    const short* __restrict__ h_ss, const int* __restrict__ pool,
    const int* __restrict__ row_ptr, const float* __restrict__ dinv_ss,
    const float* __restrict__ b_ss, float* __restrict__ out) {
  int wave = threadIdx.x >> 6, lane = threadIdx.x & 63;
  int d = blockIdx.x * 4 + wave;
  if (d >= NS_) return;
  int c = lane * 2;
  float dd = dinv_ss[d];
  float a0 = 0.f, a1 = 0.f;
  int r0 = row_ptr[2 * NA_ + d], r1 = row_ptr[2 * NA_ + d + 1];
  for (int j = r0; j < r1; ++j) {
    int s = pool[j];
    float w = dinv_ss[s] * dd;
    short2 hv = *(const short2*)&h_ss[(long)s * 128 + c];
    a0 += b2f(hv.x) * w;
    a1 += b2f(hv.y) * w;
  }
  float d2 = dd * dd;
  short2 hv = *(const short2*)&h_ss[(long)d * 128 + c];
  float2 bs = *(const float2*)&b_ss[c];
  float o0 = a0 + b2f(hv.x) * d2 + bs.x;
  float o1 = a1 + b2f(hv.y) * d2 + bs.y;
  float2 res = make_float2(fmaxf(o0, 0.f), fmaxf(o1, 0.f));
  *(float2*)&out[(long)d * 128 + c] = res;
}

extern "C" void kernel_launch(void* const* d_in, const int* in_sizes, int n_in,
                              void* d_out, int out_size, void* d_ws, size_t ws_size,
                              hipStream_t stream) {
  const float* x_a = (const float*)d_in[0];
  const float* x_s = (const float*)d_in[1];
  const int* ei_aa = (const int*)d_in[2];
  const int* ei_ss = (const int*)d_in[3];
  const int* sa_src = (const int*)d_in[4];
  const int* sa_dst = (const int*)d_in[5];
  const float* W_aa = (const float*)d_in[6];
  const float* b_aa = (const float*)d_in[7];
  const float* W_ss = (const float*)d_in[8];
  const float* b_ss = (const float*)d_in[9];
  const float* W_sal = (const float*)d_in[10];
  const float* b_sal = (const float*)d_in[11];
  const float* W_sar = (const float*)d_in[12];

  const int* src_aa = ei_aa;
  const int* dst_aa = ei_aa + EAA_;
  const int* src_ss = ei_ss;
  const int* dst_ss = ei_ss + ESS_;

  // ---- workspace (~90 MB) ----
  char* base = (char*)d_ws;
  size_t off = 0;
  auto alloc = [&](size_t bytes) {
    void* p = base + off;
    off += (bytes + 511) & ~(size_t)511;
    return p;
  };
  short* h_aa = (short*)alloc((size_t)NA_ * 128 * 2);   // 25.6 MB
  short* h_ss = (short*)alloc((size_t)NS_ * 128 * 2);   // 12.8 MB
  short* y_sl = (short*)alloc((size_t)NS_ * 128 * 2);   // 12.8 MB
  short* r_a = (short*)alloc((size_t)NA_ * 128 * 2);    // 25.6 MB
  int* pool = (int*)alloc((size_t)(EAA_ + ESA_ + ESS_) * 4);  // 8 MB
  int* cnt_all = (int*)alloc((size_t)NNODES_ * 4);
  int* part = (int*)alloc((size_t)NPAD_ * 4);
  int* row_ptr = (int*)alloc((size_t)NPAD_ * 4);
  int* cursor = (int*)alloc((size_t)NPAD_ * 4);
  int* bsums = (int*)alloc(256 * 4);
  float* dinv_aa = (float*)alloc((size_t)NA_ * 4);
  float* dinv_ss = (float*)alloc((size_t)NS_ * 4);
  float* invc_sa = (float*)alloc((size_t)NA_ * 4);
  short* Wt_aa = (short*)alloc(128 * 256 * 2);
  short* Wt_ss = (short*)alloc(128 * 256 * 2);
  short* Wt_sal = (short*)alloc(128 * 256 * 2);
  short* Wt_sar = (short*)alloc(128 * 256 * 2);

  float* out_art = (float*)d_out;
  float* out_soft = (float*)d_out + (size_t)NA_ * 128;

  int gA = (NA_ + 255) / 256, gS = (NS_ + 255) / 256;

  // ---- CSR build ----
  hipMemsetAsync(cnt_all, 0, (size_t)NNODES_ * 4, stream);
  count_k<<<(EAA_ + 255) / 256, 256, 0, stream>>>(dst_aa, cnt_all, EAA_);
  count_k<<<(ESA_ + 255) / 256, 256, 0, stream>>>(sa_dst, cnt_all + NA_, ESA_);
  count_k<<<(ESS_ + 255) / 256, 256, 0, stream>>>(dst_ss, cnt_all + 2 * NA_, ESS_);
  scanA_k<<<SCAN_BLOCKS_, 256, 0, stream>>>(cnt_all, part, bsums);
  scanB_k<<<1, 256, 0, stream>>>(bsums);
  scanC_k<<<SCAN_BLOCKS_, 256, 0, stream>>>(part, bsums, row_ptr, cursor);
  fill_k<<<(EAA_ + 255) / 256, 256, 0, stream>>>(src_aa, dst_aa, cursor, 0, pool, EAA_);
  fill_k<<<(ESA_ + 255) / 256, 256, 0, stream>>>(sa_src, sa_dst, cursor, NA_, pool, ESA_);
  fill_k<<<(ESS_ + 255) / 256, 256, 0, stream>>>(src_ss, dst_ss, cursor, 2 * NA_, pool, ESS_);
  norms_k<<<(NA_ + 255) / 256, 256, 0, stream>>>(cnt_all, dinv_aa, dinv_ss, invc_sa);

  // ---- weights + GEMMs ----
  transpose_w_k<<<128, 256, 0, stream>>>(W_aa, Wt_aa);
  transpose_w_k<<<128, 256, 0, stream>>>(W_ss, Wt_ss);
  transpose_w_k<<<128, 256, 0, stream>>>(W_sal, Wt_sal);
  transpose_w_k<<<128, 256, 0, stream>>>(W_sar, Wt_sar);
  gemm_k<<<gA, 256, 0, stream>>>(x_a, Wt_aa, h_aa, NA_);
  gemm_k<<<gA, 256, 0, stream>>>(x_a, Wt_sar, r_a, NA_);
  gemm_k<<<gS, 256, 0, stream>>>(x_s, Wt_ss, h_ss, NS_);
  gemm_k<<<gS, 256, 0, stream>>>(x_s, Wt_sal, y_sl, NS_);

  // ---- fused gathers ----
  gather_art_k<<<(NA_ + 3) / 4, 256, 0, stream>>>(h_aa, y_sl, r_a, pool, row_ptr, dinv_aa,
                                                  invc_sa, b_aa, b_sal, out_art);
  gather_soft_k<<<(NS_ + 3) / 4, 256, 0, stream>>>(h_ss, pool, row_ptr, dinv_ss, b_ss, out_soft);
}

// Round 5
// 648.402 us; speedup vs baseline: 11.4197x; 1.1556x over previous
//
#include <hip/hip_runtime.h>

typedef short short8 __attribute__((ext_vector_type(8)));
typedef float float4v __attribute__((ext_vector_type(4)));
typedef __bf16 bf16x8 __attribute__((ext_vector_type(8)));

#define NA_ 100000
#define NS_ 50000
#define EAA_ 800000
#define ESS_ 400000
#define ESA_ 800000
#define POOLE_ (EAA_ + ESA_ + ESS_)  // 2,000,000
// concatenated node index space for CSR: [aa: 0..NA_), [sa: NA_..2*NA_), [ss: 2*NA_..2*NA_+NS_)
#define NNODES_ (NA_ + NA_ + NS_)   // 250000
#define SCAN_BLOCKS_ 62             // 62*4096 = 253952 >= NNODES_+1
#define NPAD_ (SCAN_BLOCKS_ * 4096)

static __device__ __forceinline__ float b2f(short s) {
  unsigned int u = ((unsigned int)(unsigned short)s) << 16;
  return __builtin_bit_cast(float, u);
}
static __device__ __forceinline__ short f2b(float f) {
  unsigned int u = __builtin_bit_cast(unsigned int, f);
  u = u + 0x7FFFu + ((u >> 16) & 1u);
  return (short)(u >> 16);
}

// ---------------- x fp32 -> bf16 (streaming) ----------------
__global__ void cvt_k(const float* __restrict__ x, short* __restrict__ y, int n8) {
  int i = blockIdx.x * 256 + threadIdx.x;
  if (i >= n8) return;
  const float* xp = x + (long)i * 8;
  float4v a0 = *(const float4v*)xp;
  float4v a1 = *(const float4v*)(xp + 4);
  short8 r;
#pragma unroll
  for (int j = 0; j < 4; ++j) {
    r[j] = f2b(a0[j]);
    r[4 + j] = f2b(a1[j]);
  }
  *(short8*)&y[(long)i * 8] = r;
}

// ---------------- all 4 W transposes in one kernel ----------------
__global__ void transpose_all_k(const float* __restrict__ W0, const float* __restrict__ W1,
                                const float* __restrict__ W2, const float* __restrict__ W3,
                                short* __restrict__ T0, short* __restrict__ T1,
                                short* __restrict__ T2, short* __restrict__ T3) {
  int tid = blockIdx.x * 256 + threadIdx.x;  // 4 * 32768
  int which = tid >> 15, r = tid & 32767;
  const float* W = which == 0 ? W0 : which == 1 ? W1 : which == 2 ? W2 : W3;
  short* T = which == 0 ? T0 : which == 1 ? T1 : which == 2 ? T2 : T3;
  int k = r >> 7, n = r & 127;
  T[n * 256 + k] = f2b(W[k * 128 + n]);
}

// ---------------- GEMM: C[M,128] = A[M,256] @ Wt^T (A bf16, Wt bf16 [128][256]) ----------------
#define LDN 136
__global__ __launch_bounds__(256) void gemm_k(const short* __restrict__ A,
                                              const short* __restrict__ Wt,
                                              short* __restrict__ C, int M) {
  __shared__ short lds[128 * LDN];
  int tid = threadIdx.x;
  int wave = tid >> 6, lane = tid & 63;
  int l16 = lane & 15, lq = lane >> 4;
  int rowBase = blockIdx.x * 256 + wave * 64;

  float4v acc[4][8];
#pragma unroll
  for (int rt = 0; rt < 4; ++rt)
#pragma unroll
    for (int ct = 0; ct < 8; ++ct) acc[rt][ct] = (float4v){0.f, 0.f, 0.f, 0.f};

  for (int phase = 0; phase < 2; ++phase) {
    int kg = phase * 128;
    __syncthreads();
    for (int idx = tid; idx < 128 * 16; idx += 256) {
      int n = idx >> 4, c = idx & 15;
      *(short8*)&lds[n * LDN + c * 8] = *(const short8*)&Wt[n * 256 + kg + c * 8];
    }
    __syncthreads();
#pragma unroll
    for (int ks = 0; ks < 4; ++ks) {
      int k0 = kg + ks * 32;
      short8 af[4];
#pragma unroll
      for (int rt = 0; rt < 4; ++rt) {
        int row = rowBase + rt * 16 + l16;
        if (row >= M) row = M - 1;
        af[rt] = *(const short8*)&A[(long)row * 256 + k0 + lq * 8];
      }
#pragma unroll
      for (int ct = 0; ct < 8; ++ct) {
        short8 bfg = *(const short8*)&lds[(ct * 16 + l16) * LDN + ks * 32 + lq * 8];
#pragma unroll
        for (int rt = 0; rt < 4; ++rt) {
          acc[rt][ct] = __builtin_amdgcn_mfma_f32_16x16x32_bf16(
              __builtin_bit_cast(bf16x8, af[rt]), __builtin_bit_cast(bf16x8, bfg),
              acc[rt][ct], 0, 0, 0);
        }
      }
    }
  }
#pragma unroll
  for (int rt = 0; rt < 4; ++rt) {
    int r0 = rowBase + rt * 16 + lq * 4;
#pragma unroll
    for (int ct = 0; ct < 8; ++ct) {
      int col = ct * 16 + l16;
#pragma unroll
      for (int r = 0; r < 4; ++r) {
        int row = r0 + r;
        if (row < M) C[(long)row * 128 + col] = f2b(acc[rt][ct][r]);
      }
    }
  }
}

// ---------------- CSR build ----------------
__global__ void count_all_k(const int* __restrict__ dst_aa, const int* __restrict__ sa_dst,
                            const int* __restrict__ dst_ss, int* __restrict__ cnt) {
  int i = blockIdx.x * 256 + threadIdx.x;
  if (i < EAA_) atomicAdd(&cnt[dst_aa[i]], 1);
  else if (i < EAA_ + ESA_) atomicAdd(&cnt[NA_ + sa_dst[i - EAA_]], 1);
  else if (i < POOLE_) atomicAdd(&cnt[2 * NA_ + dst_ss[i - EAA_ - ESA_]], 1);
}

__global__ void scanA_k(const int* __restrict__ in, int* __restrict__ part,
                        int* __restrict__ bsums) {
  __shared__ int lds[256];
  int t = threadIdx.x, b = blockIdx.x;
  int base = b * 4096 + t * 16;
  int v[16];
  int run = 0;
#pragma unroll
  for (int j = 0; j < 16; ++j) {
    int x = (base + j < NNODES_) ? in[base + j] : 0;
    v[j] = run;
    run += x;
  }
  lds[t] = run;
  __syncthreads();
  int incl = run;
  for (int off = 1; off < 256; off <<= 1) {
    int add = (t >= off) ? lds[t - off] : 0;
    __syncthreads();
    lds[t] += add;
    incl = lds[t];
    __syncthreads();
  }
  int excl = incl - run;
#pragma unroll
  for (int j = 0; j < 16; ++j) part[base + j] = v[j] + excl;
  if (t == 255) bsums[b] = incl;
}
__global__ void scanB_k(int* __restrict__ bsums) {
  __shared__ int lds[256];
  int t = threadIdx.x;
  int v = (t < SCAN_BLOCKS_) ? bsums[t] : 0;
  lds[t] = v;
  __syncthreads();
  int incl = v;
  for (int off = 1; off < 256; off <<= 1) {
    int add = (t >= off) ? lds[t - off] : 0;
    __syncthreads();
    lds[t] += add;
    incl = lds[t];
    __syncthreads();
  }
  if (t < SCAN_BLOCKS_) bsums[t] = incl - v;
}
__global__ void scanC_k(const int* __restrict__ part, const int* __restrict__ bsums,
                        int* __restrict__ row_ptr, int* __restrict__ cursor) {
  int t = threadIdx.x, b = blockIdx.x;
  int base = b * 4096 + t * 16;
  int sb = bsums[b];
#pragma unroll
  for (int j = 0; j < 16; ++j) {
    int val = part[base + j] + sb;
    row_ptr[base + j] = val;
    cursor[base + j] = val;
  }
}
__global__ void fill_all_k(const int* __restrict__ src_aa, const int* __restrict__ dst_aa,
                           const int* __restrict__ sa_src, const int* __restrict__ sa_dst,
                           const int* __restrict__ src_ss, const int* __restrict__ dst_ss,
                           int* __restrict__ cursor, int* __restrict__ pool) {
  int i = blockIdx.x * 256 + threadIdx.x;
  int s, node;
  if (i < EAA_) { s = src_aa[i]; node = dst_aa[i]; }
  else if (i < EAA_ + ESA_) { int j = i - EAA_; s = sa_src[j]; node = NA_ + sa_dst[j]; }
  else if (i < POOLE_) { int j = i - EAA_ - ESA_; s = src_ss[j]; node = 2 * NA_ + dst_ss[j]; }
  else return;
  int pos = atomicAdd(&cursor[node], 1);
  pool[pos] = s;
}

// ---------------- norms ----------------
__global__ void norms_k(const int* __restrict__ cnt, float* __restrict__ dinv_aa,
                        float* __restrict__ dinv_ss, float* __restrict__ invc_sa) {
  int i = blockIdx.x * 256 + threadIdx.x;
  if (i < NA_) {
    dinv_aa[i] = rsqrtf((float)(cnt[i] + 1));
    invc_sa[i] = 1.0f / fmaxf((float)cnt[NA_ + i], 1.0f);
  }
  if (i < NS_) dinv_ss[i] = rsqrtf((float)(cnt[2 * NA_ + i] + 1));
}

// ---------------- fused gathers, 8-deep chunked prefetch ----------------
__global__ __launch_bounds__(256) void gather_art_k(
    const short* __restrict__ h_aa, const short* __restrict__ y_sl,
    const short* __restrict__ r_a, const int* __restrict__ pool,
    const int* __restrict__ row_ptr, const float* __restrict__ dinv_aa,
    const float* __restrict__ invc_sa, const float* __restrict__ b_aa,
    const float* __restrict__ b_sal, float* __restrict__ out) {
  int wave = threadIdx.x >> 6, lane = threadIdx.x & 63;
  int d = blockIdx.x * 4 + wave;
  if (d >= NA_) return;
  int c = lane * 2;
  float dd = dinv_aa[d];

  // GCN aa neighbors
  float a0 = 0.f, a1 = 0.f;
  {
    int r0 = row_ptr[d], r1 = row_ptr[d + 1];
    for (int jj = r0; jj < r1; jj += 8) {
      int s[8];
      float m[8];
#pragma unroll
      for (int t = 0; t < 8; ++t) {
        int j = jj + t;
        int jc = (j < r1) ? j : (POOLE_ - 1);
        s[t] = pool[jc];
        m[t] = (j < r1) ? 1.f : 0.f;
      }
      short2 hv[8];
#pragma unroll
      for (int t = 0; t < 8; ++t) hv[t] = *(const short2*)&h_aa[(long)s[t] * 128 + c];
      float wv[8];
#pragma unroll
      for (int t = 0; t < 8; ++t) wv[t] = dinv_aa[s[t]] * m[t];
#pragma unroll
      for (int t = 0; t < 8; ++t) {
        float w = wv[t] * dd;
        a0 += b2f(hv[t].x) * w;
        a1 += b2f(hv[t].y) * w;
      }
    }
  }
  // SAGE sa neighbors (mean)
  float s0 = 0.f, s1 = 0.f;
  {
    int r0 = row_ptr[NA_ + d], r1 = row_ptr[NA_ + d + 1];
    for (int jj = r0; jj < r1; jj += 8) {
      int s[8];
      float m[8];
#pragma unroll
      for (int t = 0; t < 8; ++t) {
        int j = jj + t;
        int jc = (j < r1) ? j : (POOLE_ - 1);
        s[t] = pool[jc];
        m[t] = (j < r1) ? 1.f : 0.f;
      }
      short2 yv[8];
#pragma unroll
      for (int t = 0; t < 8; ++t) yv[t] = *(const short2*)&y_sl[(long)s[t] * 128 + c];
#pragma unroll
      for (int t = 0; t < 8; ++t) {
        s0 += b2f(yv[t].x) * m[t];
        s1 += b2f(yv[t].y) * m[t];
      }
    }
  }
  float ic = invc_sa[d];
  float d2 = dd * dd;
  short2 hv = *(const short2*)&h_aa[(long)d * 128 + c];
  short2 rv = *(const short2*)&r_a[(long)d * 128 + c];
  float2 ba = *(const float2*)&b_aa[c];
  float2 bl = *(const float2*)&b_sal[c];
  float o0 = 0.5f * ((a0 + b2f(hv.x) * d2 + ba.x) + (s0 * ic + bl.x + b2f(rv.x)));
  float o1 = 0.5f * ((a1 + b2f(hv.y) * d2 + ba.y) + (s1 * ic + bl.y + b2f(rv.y)));
  float2 res = make_float2(fmaxf(o0, 0.f), fmaxf(o1, 0.f));
  *(float2*)&out[(long)d * 128 + c] = res;
}

__global__ __launch_bounds__(256) void gather_soft_k(
    const short* __restrict__ h_ss, const int* __restrict__ pool,
    const int* __restrict__ row_ptr, const float* __restrict__ dinv_ss,
    const float* __restrict__ b_ss, float* __restrict__ out) {
  int wave = threadIdx.x >> 6, lane = threadIdx.x & 63;
  int d = blockIdx.x * 4 + wave;
  if (d >= NS_) return;
  int c = lane * 2;
  float dd = dinv_ss[d];
  float a0 = 0.f, a1 = 0.f;
  int r0 = row_ptr[2 * NA_ + d], r1 = row_ptr[2 * NA_ + d + 1];
  for (int jj = r0; jj < r1; jj += 8) {
    int s[8];
    float m[8];
#pragma unroll
    for (int t = 0; t < 8; ++t) {
      int j = jj + t;
      int jc = (j < r1) ? j : (POOLE_ - 1);
      s[t] = pool[jc];
      m[t] = (j < r1) ? 1.f : 0.f;
    }
    short2 hv[8];
#pragma unroll
    for (int t = 0; t < 8; ++t) hv[t] = *(const short2*)&h_ss[(long)s[t] * 128 + c];
    float wv[8];
#pragma unroll
    for (int t = 0; t < 8; ++t) wv[t] = dinv_ss[s[t]] * m[t];
#pragma unroll
    for (int t = 0; t < 8; ++t) {
      float w = wv[t] * dd;
      a0 += b2f(hv[t].x) * w;
      a1 += b2f(hv[t].y) * w;
    }
  }
  float d2 = dd * dd;
  short2 hv = *(const short2*)&h_ss[(long)d * 128 + c];
  float2 bs = *(const float2*)&b_ss[c];
  float o0 = a0 + b2f(hv.x) * d2 + bs.x;
  float o1 = a1 + b2f(hv.y) * d2 + bs.y;
  float2 res = make_float2(fmaxf(o0, 0.f), fmaxf(o1, 0.f));
  *(float2*)&out[(long)d * 128 + c] = res;
}

extern "C" void kernel_launch(void* const* d_in, const int* in_sizes, int n_in,
                              void* d_out, int out_size, void* d_ws, size_t ws_size,
                              hipStream_t stream) {
  const float* x_a = (const float*)d_in[0];
  const float* x_s = (const float*)d_in[1];
  const int* ei_aa = (const int*)d_in[2];
  const int* ei_ss = (const int*)d_in[3];
  const int* sa_src = (const int*)d_in[4];
  const int* sa_dst = (const int*)d_in[5];
  const float* W_aa = (const float*)d_in[6];
  const float* b_aa = (const float*)d_in[7];
  const float* W_ss = (const float*)d_in[8];
  const float* b_ss = (const float*)d_in[9];
  const float* W_sal = (const float*)d_in[10];
  const float* b_sal = (const float*)d_in[11];
  const float* W_sar = (const float*)d_in[12];

  const int* src_aa = ei_aa;
  const int* dst_aa = ei_aa + EAA_;
  const int* src_ss = ei_ss;
  const int* dst_ss = ei_ss + ESS_;

  // ---- workspace (~130 MB) ----
  char* base = (char*)d_ws;
  size_t off = 0;
  auto alloc = [&](size_t bytes) {
    void* p = base + off;
    off += (bytes + 511) & ~(size_t)511;
    return p;
  };
  short* xb_a = (short*)alloc((size_t)NA_ * 256 * 2);   // 51.2 MB
  short* xb_s = (short*)alloc((size_t)NS_ * 256 * 2);   // 25.6 MB
  short* h_aa = (short*)alloc((size_t)NA_ * 128 * 2);   // 25.6 MB
  short* h_ss = (short*)alloc((size_t)NS_ * 128 * 2);   // 12.8 MB
  short* y_sl = (short*)alloc((size_t)NS_ * 128 * 2);   // 12.8 MB
  short* r_a = (short*)alloc((size_t)NA_ * 128 * 2);    // 25.6 MB
  int* pool = (int*)alloc((size_t)POOLE_ * 4);          // 8 MB
  int* cnt_all = (int*)alloc((size_t)NNODES_ * 4);
  int* part = (int*)alloc((size_t)NPAD_ * 4);
  int* row_ptr = (int*)alloc((size_t)NPAD_ * 4);
  int* cursor = (int*)alloc((size_t)NPAD_ * 4);
  int* bsums = (int*)alloc(256 * 4);
  float* dinv_aa = (float*)alloc((size_t)NA_ * 4);
  float* dinv_ss = (float*)alloc((size_t)NS_ * 4);
  float* invc_sa = (float*)alloc((size_t)NA_ * 4);
  short* Wt_aa = (short*)alloc(128 * 256 * 2);
  short* Wt_ss = (short*)alloc(128 * 256 * 2);
  short* Wt_sal = (short*)alloc(128 * 256 * 2);
  short* Wt_sar = (short*)alloc(128 * 256 * 2);

  float* out_art = (float*)d_out;
  float* out_soft = (float*)d_out + (size_t)NA_ * 128;

  int gA = (NA_ + 255) / 256, gS = (NS_ + 255) / 256;

  // ---- CSR build ----
  hipMemsetAsync(cnt_all, 0, (size_t)NNODES_ * 4, stream);
  count_all_k<<<(POOLE_ + 255) / 256, 256, 0, stream>>>(dst_aa, sa_dst, dst_ss, cnt_all);
  scanA_k<<<SCAN_BLOCKS_, 256, 0, stream>>>(cnt_all, part, bsums);
  scanB_k<<<1, 256, 0, stream>>>(bsums);
  scanC_k<<<SCAN_BLOCKS_, 256, 0, stream>>>(part, bsums, row_ptr, cursor);
  fill_all_k<<<(POOLE_ + 255) / 256, 256, 0, stream>>>(src_aa, dst_aa, sa_src, sa_dst, src_ss,
                                                       dst_ss, cursor, pool);
  norms_k<<<(NA_ + 255) / 256, 256, 0, stream>>>(cnt_all, dinv_aa, dinv_ss, invc_sa);

  // ---- weights + x conversion + GEMMs ----
  transpose_all_k<<<512, 256, 0, stream>>>(W_aa, W_ss, W_sal, W_sar, Wt_aa, Wt_ss, Wt_sal,
                                           Wt_sar);
  cvt_k<<<(NA_ * 32 + 255) / 256, 256, 0, stream>>>(x_a, xb_a, NA_ * 32);
  cvt_k<<<(NS_ * 32 + 255) / 256, 256, 0, stream>>>(x_s, xb_s, NS_ * 32);
  gemm_k<<<gA, 256, 0, stream>>>(xb_a, Wt_aa, h_aa, NA_);
  gemm_k<<<gA, 256, 0, stream>>>(xb_a, Wt_sar, r_a, NA_);
  gemm_k<<<gS, 256, 0, stream>>>(xb_s, Wt_ss, h_ss, NS_);
  gemm_k<<<gS, 256, 0, stream>>>(xb_s, Wt_sal, y_sl, NS_);

  // ---- fused gathers ----
  gather_art_k<<<(NA_ + 3) / 4, 256, 0, stream>>>(h_aa, y_sl, r_a, pool, row_ptr, dinv_aa,
                                                  invc_sa, b_aa, b_sal, out_art);
  gather_soft_k<<<(NS_ + 3) / 4, 256, 0, stream>>>(h_ss, pool, row_ptr, dinv_ss, b_ss, out_soft);
}

// Round 6
// 640.594 us; speedup vs baseline: 11.5589x; 1.0122x over previous
//
#include <hip/hip_runtime.h>

typedef short short8 __attribute__((ext_vector_type(8)));
typedef float float4v __attribute__((ext_vector_type(4)));
typedef __bf16 bf16x8 __attribute__((ext_vector_type(8)));

#define NA_ 100000
#define NS_ 50000
#define EAA_ 800000
#define ESS_ 400000
#define ESA_ 800000
#define POOLE_ (EAA_ + ESA_ + ESS_)  // 2,000,000
// concatenated node index space: [aa: 0..NA_), [sa: NA_..2*NA_), [ss: 2*NA_..2*NA_+NS_)
#define NNODES_ (NA_ + NA_ + NS_)   // 250000
#define SCAN_BLOCKS_ 62             // 62*4096 = 253952 >= NNODES_+1
#define NPAD_ (SCAN_BLOCKS_ * 4096)

static __device__ __forceinline__ float b2f(short s) {
  unsigned int u = ((unsigned int)(unsigned short)s) << 16;
  return __builtin_bit_cast(float, u);
}
static __device__ __forceinline__ short f2b(float f) {
  unsigned int u = __builtin_bit_cast(unsigned int, f);
  u = u + 0x7FFFu + ((u >> 16) & 1u);
  return (short)(u >> 16);
}

// ---------------- x fp32 -> bf16 (streaming) ----------------
__global__ void cvt_k(const float* __restrict__ x, short* __restrict__ y, int n8) {
  int i = blockIdx.x * 256 + threadIdx.x;
  if (i >= n8) return;
  const float* xp = x + (long)i * 8;
  float4v a0 = *(const float4v*)xp;
  float4v a1 = *(const float4v*)(xp + 4);
  short8 r;
#pragma unroll
  for (int j = 0; j < 4; ++j) {
    r[j] = f2b(a0[j]);
    r[4 + j] = f2b(a1[j]);
  }
  *(short8*)&y[(long)i * 8] = r;
}

// ---------------- all 4 W transposes in one kernel ----------------
__global__ void transpose_all_k(const float* __restrict__ W0, const float* __restrict__ W1,
                                const float* __restrict__ W2, const float* __restrict__ W3,
                                short* __restrict__ T0, short* __restrict__ T1,
                                short* __restrict__ T2, short* __restrict__ T3) {
  int tid = blockIdx.x * 256 + threadIdx.x;  // 4 * 32768
  int which = tid >> 15, r = tid & 32767;
  const float* W = which == 0 ? W0 : which == 1 ? W1 : which == 2 ? W2 : W3;
  short* T = which == 0 ? T0 : which == 1 ? T1 : which == 2 ? T2 : T3;
  int k = r >> 7, n = r & 127;
  T[n * 256 + k] = f2b(W[k * 128 + n]);
}

// ---------------- fused dual GEMM: C0,C1[M,128] = A[M,256] @ {Wt0,Wt1}^T ----------------
// A bf16 row-major; Wt0/Wt1 bf16 [128][256]. Block = 256 thr = 4 waves x 32 rows = 128 rows.
// LDS: 256 stacked N-rows (128 per weight) x 64-K-tile, stride 72 shorts (144B = 36 dw,
// 36 mod 32 = 4 -> 2-way bank alias = free, same pattern as proven LDN=136).
#define LDK 72
__global__ __launch_bounds__(256) void gemm2_k(const short* __restrict__ A,
                                               const short* __restrict__ Wt0,
                                               const short* __restrict__ Wt1,
                                               short* __restrict__ C0,
                                               short* __restrict__ C1, int M) {
  __shared__ short lds[256 * LDK];
  int tid = threadIdx.x;
  int wave = tid >> 6, lane = tid & 63;
  int l16 = lane & 15, lq = lane >> 4;
  int rowBase = blockIdx.x * 128 + wave * 32;

  float4v acc[2][16];
#pragma unroll
  for (int rt = 0; rt < 2; ++rt)
#pragma unroll
    for (int ct = 0; ct < 16; ++ct) acc[rt][ct] = (float4v){0.f, 0.f, 0.f, 0.f};

  for (int p = 0; p < 4; ++p) {
    int kp = p * 64;
    __syncthreads();
    // stage both weights' K-slice [*, kp:kp+64] into LDS (2048 short8 chunks)
    for (int idx = tid; idx < 2048; idx += 256) {
      int row = idx >> 3, c = idx & 7;  // row 0..255, c 0..7
      const short* Wsrc = (row < 128) ? &Wt0[row * 256] : &Wt1[(row - 128) * 256];
      *(short8*)&lds[row * LDK + c * 8] = *(const short8*)&Wsrc[kp + c * 8];
    }
    __syncthreads();
#pragma unroll
    for (int ks = 0; ks < 2; ++ks) {
      int k0 = kp + ks * 32;
      short8 af[2];
#pragma unroll
      for (int rt = 0; rt < 2; ++rt) {
        int row = rowBase + rt * 16 + l16;
        if (row >= M) row = M - 1;
        af[rt] = *(const short8*)&A[(long)row * 256 + k0 + lq * 8];
      }
#pragma unroll
      for (int ct = 0; ct < 16; ++ct) {
        short8 bfg = *(const short8*)&lds[(ct * 16 + l16) * LDK + ks * 32 + lq * 8];
#pragma unroll
        for (int rt = 0; rt < 2; ++rt) {
          acc[rt][ct] = __builtin_amdgcn_mfma_f32_16x16x32_bf16(
              __builtin_bit_cast(bf16x8, af[rt]), __builtin_bit_cast(bf16x8, bfg),
              acc[rt][ct], 0, 0, 0);
        }
      }
    }
  }
#pragma unroll
  for (int rt = 0; rt < 2; ++rt) {
    int r0 = rowBase + rt * 16 + lq * 4;
#pragma unroll
    for (int ct = 0; ct < 16; ++ct) {
      short* C = (ct < 8) ? C0 : C1;
      int col = (ct & 7) * 16 + l16;
#pragma unroll
      for (int r = 0; r < 4; ++r) {
        int row = r0 + r;
        if (row < M) C[(long)row * 128 + col] = f2b(acc[rt][ct][r]);
      }
    }
  }
}

// ---------------- CSR pass 1: count + per-edge rank (coalesced pos store) ----------------
__global__ void count_pos_k(const int* __restrict__ dst_aa, const int* __restrict__ sa_dst,
                            const int* __restrict__ dst_ss, int* __restrict__ cnt,
                            int* __restrict__ pos) {
  int i = blockIdx.x * 256 + threadIdx.x;
  int node;
  if (i < EAA_) node = dst_aa[i];
  else if (i < EAA_ + ESA_) node = NA_ + sa_dst[i - EAA_];
  else if (i < POOLE_) node = 2 * NA_ + dst_ss[i - EAA_ - ESA_];
  else return;
  pos[i] = atomicAdd(&cnt[node], 1);
}

// ---------------- scans ----------------
__global__ void scanA_k(const int* __restrict__ in, int* __restrict__ part,
                        int* __restrict__ bsums) {
  __shared__ int lds[256];
  int t = threadIdx.x, b = blockIdx.x;
  int base = b * 4096 + t * 16;
  int v[16];
  int run = 0;
#pragma unroll
  for (int j = 0; j < 16; ++j) {
    int x = (base + j < NNODES_) ? in[base + j] : 0;
    v[j] = run;
    run += x;
  }
  lds[t] = run;
  __syncthreads();
  int incl = run;
  for (int off = 1; off < 256; off <<= 1) {
    int add = (t >= off) ? lds[t - off] : 0;
    __syncthreads();
    lds[t] += add;
    incl = lds[t];
    __syncthreads();
  }
  int excl = incl - run;
#pragma unroll
  for (int j = 0; j < 16; ++j) part[base + j] = v[j] + excl;
  if (t == 255) bsums[b] = incl;
}
__global__ void scanB_k(int* __restrict__ bsums) {
  __shared__ int lds[256];
  int t = threadIdx.x;
  int v = (t < SCAN_BLOCKS_) ? bsums[t] : 0;
  lds[t] = v;
  __syncthreads();
  int incl = v;
  for (int off = 1; off < 256; off <<= 1) {
    int add = (t >= off) ? lds[t - off] : 0;
    __syncthreads();
    lds[t] += add;
    incl = lds[t];
    __syncthreads();
  }
  if (t < SCAN_BLOCKS_) bsums[t] = incl - v;
}
// scanC: finalize row_ptr + fused norms (dinv/invc from cnt)
__global__ void scanC_k(const int* __restrict__ part, const int* __restrict__ bsums,
                        const int* __restrict__ cnt, int* __restrict__ row_ptr,
                        float* __restrict__ dinv_aa, float* __restrict__ dinv_ss,
                        float* __restrict__ invc_sa) {
  int t = threadIdx.x, b = blockIdx.x;
  int base = b * 4096 + t * 16;
  int sb = bsums[b];
#pragma unroll
  for (int j = 0; j < 16; ++j) {
    int i = base + j;
    row_ptr[i] = part[i] + sb;
    if (i < NA_) dinv_aa[i] = rsqrtf((float)(cnt[i] + 1));
    else if (i < 2 * NA_) invc_sa[i - NA_] = 1.0f / fmaxf((float)cnt[i], 1.0f);
    else if (i < NNODES_) dinv_ss[i - 2 * NA_] = rsqrtf((float)(cnt[i] + 1));
  }
}

// ---------------- CSR pass 2: plain-store fill, 8B entries (src, weight) ----------------
__global__ void fill2_k(const int* __restrict__ src_aa, const int* __restrict__ dst_aa,
                        const int* __restrict__ sa_src, const int* __restrict__ sa_dst,
                        const int* __restrict__ src_ss, const int* __restrict__ dst_ss,
                        const int* __restrict__ row_ptr, const int* __restrict__ pos,
                        const float* __restrict__ dinv_aa, const float* __restrict__ dinv_ss,
                        const float* __restrict__ invc_sa, int2* __restrict__ pool) {
  int i = blockIdx.x * 256 + threadIdx.x;
  int s, node;
  float w;
  if (i < EAA_) {
    s = src_aa[i];
    int d = dst_aa[i];
    node = d;
    w = dinv_aa[s] * dinv_aa[d];
  } else if (i < EAA_ + ESA_) {
    int j = i - EAA_;
    s = sa_src[j];
    int d = sa_dst[j];
    node = NA_ + d;
    w = invc_sa[d];
  } else if (i < POOLE_) {
    int j = i - EAA_ - ESA_;
    s = src_ss[j];
    int d = dst_ss[j];
    node = 2 * NA_ + d;
    w = dinv_ss[s] * dinv_ss[d];
  } else
    return;
  pool[row_ptr[node] + pos[i]] = make_int2(s, __builtin_bit_cast(int, w));
}

// ---------------- fused gathers, 8-deep chunked prefetch, weight-in-pool ----------------
__global__ __launch_bounds__(256) void gather_art_k(
    const short* __restrict__ h_aa, const short* __restrict__ y_sl,
    const short* __restrict__ r_a, const int2* __restrict__ pool,
    const int* __restrict__ row_ptr, const float* __restrict__ dinv_aa,
    const float* __restrict__ b_aa, const float* __restrict__ b_sal,
    float* __restrict__ out) {
  int wave = threadIdx.x >> 6, lane = threadIdx.x & 63;
  int d = blockIdx.x * 4 + wave;
  if (d >= NA_) return;
  int c = lane * 2;

  // GCN aa neighbors (weight = dinv[s]*dinv[d], precomputed)
  float a0 = 0.f, a1 = 0.f;
  {
    int r0 = row_ptr[d], r1 = row_ptr[d + 1];
    for (int jj = r0; jj < r1; jj += 8) {
      int2 pv[8];
      float m[8];
#pragma unroll
      for (int t = 0; t < 8; ++t) {
        int j = jj + t;
        int jc = (j < r1) ? j : (POOLE_ - 1);
        pv[t] = pool[jc];
        m[t] = (j < r1) ? 1.f : 0.f;
      }
      short2 hv[8];
#pragma unroll
      for (int t = 0; t < 8; ++t) hv[t] = *(const short2*)&h_aa[(long)pv[t].x * 128 + c];
#pragma unroll
      for (int t = 0; t < 8; ++t) {
        float w = __builtin_bit_cast(float, pv[t].y) * m[t];
        a0 += b2f(hv[t].x) * w;
        a1 += b2f(hv[t].y) * w;
      }
    }
  }
  // SAGE sa neighbors (weight = invc[d], precomputed -> sum is already the mean)
  float s0 = 0.f, s1 = 0.f;
  {
    int r0 = row_ptr[NA_ + d], r1 = row_ptr[NA_ + d + 1];
    for (int jj = r0; jj < r1; jj += 8) {
      int2 pv[8];
      float m[8];
#pragma unroll
      for (int t = 0; t < 8; ++t) {
        int j = jj + t;
        int jc = (j < r1) ? j : (POOLE_ - 1);
        pv[t] = pool[jc];
        m[t] = (j < r1) ? 1.f : 0.f;
      }
      short2 yv[8];
#pragma unroll
      for (int t = 0; t < 8; ++t) yv[t] = *(const short2*)&y_sl[(long)pv[t].x * 128 + c];
#pragma unroll
      for (int t = 0; t < 8; ++t) {
        float w = __builtin_bit_cast(float, pv[t].y) * m[t];
        s0 += b2f(yv[t].x) * w;
        s1 += b2f(yv[t].y) * w;
      }
    }
  }
  float dd = dinv_aa[d];
  float d2 = dd * dd;
  short2 hv = *(const short2*)&h_aa[(long)d * 128 + c];
  short2 rv = *(const short2*)&r_a[(long)d * 128 + c];
  float2 ba = *(const float2*)&b_aa[c];
  float2 bl = *(const float2*)&b_sal[c];
  float o0 = 0.5f * ((a0 + b2f(hv.x) * d2 + ba.x) + (s0 + bl.x + b2f(rv.x)));
  float o1 = 0.5f * ((a1 + b2f(hv.y) * d2 + ba.y) + (s1 + bl.y + b2f(rv.y)));
  float2 res = make_float2(fmaxf(o0, 0.f), fmaxf(o1, 0.f));
  *(float2*)&out[(long)d * 128 + c] = res;
}

__global__ __launch_bounds__(256) void gather_soft_k(
    const short* __restrict__ h_ss, const int2* __restrict__ pool,
    const int* __restrict__ row_ptr, const float* __restrict__ dinv_ss,
    const float* __restrict__ b_ss, float* __restrict__ out) {
  int wave = threadIdx.x >> 6, lane = threadIdx.x & 63;
  int d = blockIdx.x * 4 + wave;
  if (d >= NS_) return;
  int c = lane * 2;
  float a0 = 0.f, a1 = 0.f;
  int r0 = row_ptr[2 * NA_ + d], r1 = row_ptr[2 * NA_ + d + 1];
  for (int jj = r0; jj < r1; jj += 8) {
    int2 pv[8];
    float m[8];
#pragma unroll
    for (int t = 0; t < 8; ++t) {
      int j = jj + t;
      int jc = (j < r1) ? j : (POOLE_ - 1);
      pv[t] = pool[jc];
      m[t] = (j < r1) ? 1.f : 0.f;
    }
    short2 hv[8];
#pragma unroll
    for (int t = 0; t < 8; ++t) hv[t] = *(const short2*)&h_ss[(long)pv[t].x * 128 + c];
#pragma unroll
    for (int t = 0; t < 8; ++t) {
      float w = __builtin_bit_cast(float, pv[t].y) * m[t];
      a0 += b2f(hv[t].x) * w;
      a1 += b2f(hv[t].y) * w;
    }
  }
  float dd = dinv_ss[d];
  float d2 = dd * dd;
  short2 hv = *(const short2*)&h_ss[(long)d * 128 + c];
  float2 bs = *(const float2*)&b_ss[c];
  float o0 = a0 + b2f(hv.x) * d2 + bs.x;
  float o1 = a1 + b2f(hv.y) * d2 + bs.y;
  float2 res = make_float2(fmaxf(o0, 0.f), fmaxf(o1, 0.f));
  *(float2*)&out[(long)d * 128 + c] = res;
}

extern "C" void kernel_launch(void* const* d_in, const int* in_sizes, int n_in,
                              void* d_out, int out_size, void* d_ws, size_t ws_size,
                              hipStream_t stream) {
  const float* x_a = (const float*)d_in[0];
  const float* x_s = (const float*)d_in[1];
  const int* ei_aa = (const int*)d_in[2];
  const int* ei_ss = (const int*)d_in[3];
  const int* sa_src = (const int*)d_in[4];
  const int* sa_dst = (const int*)d_in[5];
  const float* W_aa = (const float*)d_in[6];
  const float* b_aa = (const float*)d_in[7];
  const float* W_ss = (const float*)d_in[8];
  const float* b_ss = (const float*)d_in[9];
  const float* W_sal = (const float*)d_in[10];
  const float* b_sal = (const float*)d_in[11];
  const float* W_sar = (const float*)d_in[12];

  const int* src_aa = ei_aa;
  const int* dst_aa = ei_aa + EAA_;
  const int* src_ss = ei_ss;
  const int* dst_ss = ei_ss + ESS_;

  // ---- workspace (~180 MB) ----
  char* base = (char*)d_ws;
  size_t off = 0;
  auto alloc = [&](size_t bytes) {
    void* p = base + off;
    off += (bytes + 511) & ~(size_t)511;
    return p;
  };
  short* xb_a = (short*)alloc((size_t)NA_ * 256 * 2);   // 51.2 MB
  short* xb_s = (short*)alloc((size_t)NS_ * 256 * 2);   // 25.6 MB
  short* h_aa = (short*)alloc((size_t)NA_ * 128 * 2);   // 25.6 MB
  short* h_ss = (short*)alloc((size_t)NS_ * 128 * 2);   // 12.8 MB
  short* y_sl = (short*)alloc((size_t)NS_ * 128 * 2);   // 12.8 MB
  short* r_a = (short*)alloc((size_t)NA_ * 128 * 2);    // 25.6 MB
  int2* pool = (int2*)alloc((size_t)POOLE_ * 8);        // 16 MB
  int* pos = (int*)alloc((size_t)POOLE_ * 4);           // 8 MB
  int* cnt_all = (int*)alloc((size_t)NNODES_ * 4);
  int* part = (int*)alloc((size_t)NPAD_ * 4);
  int* row_ptr = (int*)alloc((size_t)NPAD_ * 4);
  int* bsums = (int*)alloc(256 * 4);
  float* dinv_aa = (float*)alloc((size_t)NA_ * 4);
  float* dinv_ss = (float*)alloc((size_t)NS_ * 4);
  float* invc_sa = (float*)alloc((size_t)NA_ * 4);
  short* Wt_aa = (short*)alloc(128 * 256 * 2);
  short* Wt_ss = (short*)alloc(128 * 256 * 2);
  short* Wt_sal = (short*)alloc(128 * 256 * 2);
  short* Wt_sar = (short*)alloc(128 * 256 * 2);

  float* out_art = (float*)d_out;
  float* out_soft = (float*)d_out + (size_t)NA_ * 128;

  // ---- CSR build (two-pass, atomic-free fill) ----
  hipMemsetAsync(cnt_all, 0, (size_t)NNODES_ * 4, stream);
  count_pos_k<<<(POOLE_ + 255) / 256, 256, 0, stream>>>(dst_aa, sa_dst, dst_ss, cnt_all, pos);
  scanA_k<<<SCAN_BLOCKS_, 256, 0, stream>>>(cnt_all, part, bsums);
  scanB_k<<<1, 256, 0, stream>>>(bsums);
  scanC_k<<<SCAN_BLOCKS_, 256, 0, stream>>>(part, bsums, cnt_all, row_ptr, dinv_aa, dinv_ss,
                                            invc_sa);
  fill2_k<<<(POOLE_ + 255) / 256, 256, 0, stream>>>(src_aa, dst_aa, sa_src, sa_dst, src_ss,
                                                    dst_ss, row_ptr, pos, dinv_aa, dinv_ss,
                                                    invc_sa, pool);

  // ---- weights + x conversion + fused GEMMs ----
  transpose_all_k<<<512, 256, 0, stream>>>(W_aa, W_ss, W_sal, W_sar, Wt_aa, Wt_ss, Wt_sal,
                                           Wt_sar);
  cvt_k<<<(NA_ * 32 + 255) / 256, 256, 0, stream>>>(x_a, xb_a, NA_ * 32);
  cvt_k<<<(NS_ * 32 + 255) / 256, 256, 0, stream>>>(x_s, xb_s, NS_ * 32);
  gemm2_k<<<(NA_ + 127) / 128, 256, 0, stream>>>(xb_a, Wt_aa, Wt_sar, h_aa, r_a, NA_);
  gemm2_k<<<(NS_ + 127) / 128, 256, 0, stream>>>(xb_s, Wt_ss, Wt_sal, h_ss, y_sl, NS_);

  // ---- fused gathers ----
  gather_art_k<<<(NA_ + 3) / 4, 256, 0, stream>>>(h_aa, y_sl, r_a, pool, row_ptr, dinv_aa,
                                                  b_aa, b_sal, out_art);
  gather_soft_k<<<(NS_ + 3) / 4, 256, 0, stream>>>(h_ss, pool, row_ptr, dinv_ss, b_ss, out_soft);
}